// Round 4
// baseline (606.488 us; speedup 1.0000x reference)
//
#include <hip/hip_runtime.h>

typedef __bf16 bf16;
typedef __bf16 bf16x4 __attribute__((ext_vector_type(4)));
typedef __bf16 bf16x8 __attribute__((ext_vector_type(8)));
typedef float f32x4 __attribute__((ext_vector_type(4)));
typedef float f32x2 __attribute__((ext_vector_type(2)));
typedef _Float16 f16x2 __attribute__((ext_vector_type(2)));

#define S 2048
#define DM 2048
#define HD 128
#define H 16
#define NQKV 3072
#define NEWTON_ITERS 12
#define BROW 556         // f32 row stride of LDS buf; 556%32=12 -> quads 2-way only
#define MASKV -30000.0f  // causal-mask value; f16-representable, dominates all real scores

__device__ __forceinline__ void gl2lds16(const void* g, void* l) {
    __builtin_amdgcn_global_load_lds(
        (const __attribute__((address_space(1))) void*)g,
        (__attribute__((address_space(3))) void*)l, 16, 0, 0);
}

__device__ __forceinline__ void nt_store4(f32x4 v, float* p) {
    __builtin_nontemporal_store(v, (f32x4*)p);
}

// ---------------- DPP-based wave(64) reductions: VALU-latency chains, no LDS pipe ----------------
template <int CTRL, int RM>
__device__ __forceinline__ float dpp_zero(float x) {  // invalid/disabled lanes contribute 0
    return __builtin_bit_cast(float, __builtin_amdgcn_update_dpp(
        0, __builtin_bit_cast(int, x), CTRL, RM, 0xf, false));
}
template <int CTRL, int RM>
__device__ __forceinline__ float dpp_self(float x) {  // invalid/disabled lanes contribute x (no-op for max)
    int xi = __builtin_bit_cast(int, x);
    return __builtin_bit_cast(float, __builtin_amdgcn_update_dpp(xi, xi, CTRL, RM, 0xf, false));
}
__device__ __forceinline__ float wave_bcast63(float x) {
    return __builtin_bit_cast(float, __builtin_amdgcn_readlane(__builtin_bit_cast(int, x), 63));
}
__device__ __forceinline__ float wave_sum(float x) {
    x += dpp_zero<0x111, 0xf>(x);  // row_shr:1
    x += dpp_zero<0x112, 0xf>(x);  // row_shr:2
    x += dpp_zero<0x114, 0xf>(x);  // row_shr:4
    x += dpp_zero<0x118, 0xf>(x);  // row_shr:8  -> lane15 of each row-of-16 = row sum
    x += dpp_zero<0x142, 0xa>(x);  // row_bcast:15 -> rows 1,3
    x += dpp_zero<0x143, 0xc>(x);  // row_bcast:31 -> rows 2,3; lane63 = total
    return wave_bcast63(x);
}
__device__ __forceinline__ float wave_fmax(float x) {
    x = fmaxf(x, dpp_self<0x111, 0xf>(x));
    x = fmaxf(x, dpp_self<0x112, 0xf>(x));
    x = fmaxf(x, dpp_self<0x114, 0xf>(x));
    x = fmaxf(x, dpp_self<0x118, 0xf>(x));
    x = fmaxf(x, dpp_self<0x142, 0xa>(x));
    x = fmaxf(x, dpp_self<0x143, 0xc>(x));
    return wave_bcast63(x);
}

// ---------------- fused fp32 -> bf16 convert for all 5 inputs (float4 granules) ----------------
__global__ void cvt_all(const float* __restrict__ hid, const float* __restrict__ wq,
                        const float* __restrict__ wk, const float* __restrict__ wv,
                        const float* __restrict__ wo, bf16* __restrict__ bh,
                        bf16* __restrict__ bqkv, bf16* __restrict__ bwo) {
    int i = blockIdx.x * blockDim.x + threadIdx.x;
    const float* src;
    bf16* dst;
    int off;
    if (i < 1048576) { src = hid; dst = bh; off = i; }
    else if (i < 2097152) { src = wq; dst = bqkv; off = i - 1048576; }
    else if (i < 2359296) { src = wk; dst = bqkv + 2048 * 2048; off = i - 2097152; }
    else if (i < 2621440) { src = wv; dst = bqkv + 2048 * 2048 + 512 * 2048; off = i - 2359296; }
    else { src = wo; dst = bwo; off = i - 2621440; }
    float4 f = ((const float4*)src)[off];
    bf16x4 o;
    o[0] = (bf16)f.x; o[1] = (bf16)f.y; o[2] = (bf16)f.z; o[3] = (bf16)f.w;
    ((bf16x4*)dst)[off] = o;
}

// ---------------- BMxBN-tile GEMM: C[m][n] = sum_k A[m][k]*B[n][k] ----------------
template <int BM, int BN>
__global__ __launch_bounds__(256) void gemm_bt(const bf16* __restrict__ A,
                                               const bf16* __restrict__ B,
                                               float* __restrict__ C, int Ndim, int K) {
    __shared__ bf16 As[BM * 32];
    __shared__ bf16 Bs[BN * 32];
    int m0 = blockIdx.x * BM, n0 = blockIdx.y * BN;
    int t = threadIdx.x;
    int l = t & 63, w = t >> 6;
    int lane16 = l & 15, quad = l >> 4;

    const bf16* Abase = A + (size_t)m0 * K;
    const bf16* Bbase = B + (size_t)n0 * K;

    constexpr int MI = BM / 32, NI = BN / 32;
    int wm = (w & 1) * (BM / 2), wn = (w >> 1) * (BN / 2);
    f32x4 acc[MI][NI];
#pragma unroll
    for (int i = 0; i < MI; i++)
#pragma unroll
        for (int j = 0; j < NI; j++) acc[i][j] = (f32x4){0.f, 0.f, 0.f, 0.f};

    constexpr int AG = BM * 4;  // 16B granules in A tile
    constexpr int BG = BN * 4;

    for (int k0 = 0; k0 < K; k0 += 32) {
#pragma unroll
        for (int it = 0; it < AG / 256; it++) {
            int c = it * 256 + t;  // granule index; c - l is wave-uniform
            gl2lds16(Abase + (size_t)(c >> 2) * K + k0 + (c & 3) * 8, &As[(c - l) * 8]);
        }
#pragma unroll
        for (int it = 0; it < BG / 256; it++) {
            int c = it * 256 + t;
            gl2lds16(Bbase + (size_t)(c >> 2) * K + k0 + (c & 3) * 8, &Bs[(c - l) * 8]);
        }
        __syncthreads();
        bf16x8 af[MI], bfr[NI];
#pragma unroll
        for (int i = 0; i < MI; i++)
            af[i] = *(const bf16x8*)&As[(wm + i * 16 + lane16) * 32 + quad * 8];
#pragma unroll
        for (int j = 0; j < NI; j++)
            bfr[j] = *(const bf16x8*)&Bs[(wn + j * 16 + lane16) * 32 + quad * 8];
#pragma unroll
        for (int i = 0; i < MI; i++)
#pragma unroll
            for (int j = 0; j < NI; j++)
                acc[i][j] = __builtin_amdgcn_mfma_f32_16x16x32_bf16(af[i], bfr[j], acc[i][j], 0, 0, 0);
        __syncthreads();
    }
#pragma unroll
    for (int i = 0; i < MI; i++)
#pragma unroll
        for (int j = 0; j < NI; j++) {
            float* cp = C + (size_t)(m0 + wm + i * 16 + quad * 4) * Ndim + n0 + wn + j * 16 + lane16;
#pragma unroll
            for (int r = 0; r < 4; r++) cp[(size_t)r * Ndim] = acc[i][j][r];
        }
}

// ---------------- RoPE for q/k (cols 0..2559), coalesced in col ----------------
__global__ void rope_qk(const float* __restrict__ qkv, const float* __restrict__ cosb,
                        const float* __restrict__ sinb, bf16* __restrict__ qs,
                        bf16* __restrict__ kb) {
    int col = blockIdx.x * 256 + threadIdx.x;  // 0..2559
    int s = blockIdx.y;
    const float* row = qkv + (size_t)s * NQKV;
    float v = row[col];
    if (col < DM) {
        int h = col >> 7, d = col & 127;
        float c = cosb[s * HD + d], sn = sinb[s * HD + d];
        float other = row[(h << 7) + ((d < 64) ? (d + 64) : (d - 64))];
        float rot = (d < 64) ? -other : other;
        float o = v * c + rot * sn;
        qs[((size_t)h * S + s) * HD + d] = (bf16)(o * 0.04419417382415922f);  // HD^-0.5 * (alpha-1)
    } else {
        int c2 = col - DM;
        int kv = c2 >> 7, d = c2 & 127;
        float c = cosb[s * HD + d], sn = sinb[s * HD + d];
        float other = row[DM + (kv << 7) + ((d < 64) ? (d + 64) : (d - 64))];
        float rot = (d < 64) ? -other : other;
        float o = v * c + rot * sn;
        kb[((size_t)kv * S + s) * HD + d] = (bf16)o;
    }
}

// ---------------- V transpose via LDS tile: qkv[s][2560+y] -> vT[y][s] bf16 ----------------
__global__ __launch_bounds__(256) void vtrans(const float* __restrict__ qkv, bf16* __restrict__ vT) {
    __shared__ bf16 tile[64][66];
    int s0 = blockIdx.x * 64, y0 = blockIdx.y * 64;
    int t = threadIdx.x;
    int ty = t & 63, tr = t >> 6;
#pragma unroll
    for (int i = 0; i < 16; i++) {
        int s = tr + i * 4;
        float v = qkv[(size_t)(s0 + s) * NQKV + 2560 + y0 + ty];  // coalesced read
        tile[s][ty] = (bf16)v;
    }
    __syncthreads();
#pragma unroll
    for (int i = 0; i < 16; i++) {
        int y = tr + i * 4;
        vT[(size_t)(y0 + y) * S + s0 + ty] = tile[ty][y];  // coalesced write
    }
}

// ------- fused: scores (MFMA) + causal mask + entmax Newton + P.V (MFMA) + attn write -------
// Score row lives in registers as PACKED f16x2 (16 VGPR for 32 values) so the whole body
// fits the 64-reg budget of 8 waves/EU (2 x 16-wave blocks per CU) with NO scratch spill.
template <int SEGS>
__device__ __forceinline__ void attn_body(const bf16* __restrict__ qs, const bf16* __restrict__ kb,
                                          const bf16* __restrict__ vT, float* __restrict__ attn,
                                          bf16* __restrict__ o, int r0, int h,
                                          float (&buf)[16][BROW]) {
    constexpr int NREG2 = SEGS * 4;  // f16x2 regs per lane (= SEGS*8 scores)
    int jlen = r0 + 16;
    int l = threadIdx.x & 63;
    int w = threadIdx.x >> 6;
    int lane16 = l & 15, quad = l >> 4;

    const bf16* qrow = qs + ((size_t)h * S + (r0 + lane16)) * HD + quad * 8;
    bf16x8 afrag[4];
#pragma unroll
    for (int kc = 0; kc < 4; kc++) afrag[kc] = *(const bf16x8*)(qrow + kc * 32);

    const bf16* kbase = kb + (size_t)(h >> 2) * S * HD;
    const bf16* vbase = vT + (size_t)(h >> 2) * HD * S;
    f16x2 xr[NREG2];

    // ---- Phase A: scores into packed-f16 registers; single f32 buffer, 2 barriers/segment ----
#pragma unroll
    for (int sgi = 0; sgi < SEGS; sgi++) {
        int j0 = sgi * 512;
        float (*sb)[BROW] = buf;
#pragma unroll
        for (int tt = 0; tt < 2; tt++) {
            int t = w + tt * 16;
            int jt = j0 + t * 16;
            if (jt < jlen) {
                f32x4 acc = {0.f, 0.f, 0.f, 0.f};
                const bf16* kp = kbase + (size_t)(jt + lane16) * HD + quad * 8;
#pragma unroll
                for (int kc = 0; kc < 4; kc++) {
                    bf16x8 b = *(const bf16x8*)(kp + kc * 32);
                    acc = __builtin_amdgcn_mfma_f32_16x16x32_bf16(afrag[kc], b, acc, 0, 0, 0);
                }
                if (jt + 15 > r0) {  // diagonal tile: apply causal mask
                    int jj = jt + lane16;
#pragma unroll
                    for (int r = 0; r < 4; r++) {
                        int rowi = quad * 4 + r;
                        float v = acc[r];
                        if (jj > r0 + rowi) v = MASKV;
                        sb[rowi][t * 16 + lane16] = v;
                    }
                } else {
#pragma unroll
                    for (int r = 0; r < 4; r++) sb[quad * 4 + r][t * 16 + lane16] = acc[r];
                }
            }
        }
        __syncthreads();
#pragma unroll
        for (int part = 0; part < 2; part++) {
            float4 fq = *(const float4*)&sb[w][part * 256 + l * 4];
            f32x2 lo, hi;
            if (sgi == SEGS - 1) {
                int jb = j0 + part * 256 + l * 4;
                lo = (f32x2){(jb + 0 < jlen) ? fq.x : MASKV, (jb + 1 < jlen) ? fq.y : MASKV};
                hi = (f32x2){(jb + 2 < jlen) ? fq.z : MASKV, (jb + 3 < jlen) ? fq.w : MASKV};
            } else {
                lo = (f32x2){fq.x, fq.y};
                hi = (f32x2){fq.z, fq.w};
            }
            xr[sgi * 4 + part * 2 + 0] = __builtin_convertvector(lo, f16x2);
            xr[sgi * 4 + part * 2 + 1] = __builtin_convertvector(hi, f16x2);
        }
        __syncthreads();  // protect buffer before next segment's writes (also orders A-reads before C-writes)
    }

    // ---- Phase B: entmax-1.5 tau via Newton-from-below (wave w owns row r0+w) ----
    const f32x2 z2 = {0.f, 0.f};
    float mx = MASKV;
#pragma unroll
    for (int c = 0; c < NREG2; c++) {
        f32x2 x0 = __builtin_convertvector(xr[c], f32x2);
        mx = fmaxf(mx, fmaxf(x0[0], x0[1]));
    }
    float m = wave_fmax(mx);

    float tau = m - 1.0f;
#pragma unroll 1
    for (int it = 0; it < NEWTON_ITERS; it++) {
        f32x2 tvi = {tau, tau};
        f32x2 fa = z2, fb = z2, ga = z2, gb = z2;
#pragma unroll
        for (int c = 0; c < NREG2; c += 2) {
            f32x2 x0 = __builtin_convertvector(xr[c], f32x2);
            f32x2 t0 = __builtin_elementwise_max(x0 - tvi, z2);
            fa += t0 * t0; ga += t0;
            f32x2 x1 = __builtin_convertvector(xr[c + 1], f32x2);
            f32x2 t1 = __builtin_elementwise_max(x1 - tvi, z2);
            fb += t1 * t1; gb += t1;
        }
        f32x2 fv = fa + fb, gv = ga + gb;
        float f = wave_sum(fv[0] + fv[1]);
        float g = wave_sum(gv[0] + gv[1]);
        tau += (f - 1.0f) / (2.0f * g + 1e-20f);
    }

    f32x2 tv = {tau, tau};
    float inv;
    {
        f32x2 sa = z2, sbv = z2;
#pragma unroll
        for (int c = 0; c < NREG2; c += 2) {
            f32x2 x0 = __builtin_convertvector(xr[c], f32x2);
            f32x2 t0 = __builtin_elementwise_max(x0 - tv, z2);
            sa += t0 * t0;
            f32x2 x1 = __builtin_convertvector(xr[c + 1], f32x2);
            f32x2 t1 = __builtin_elementwise_max(x1 - tv, z2);
            sbv += t1 * t1;
        }
        f32x2 sv = sa + sbv;
        float ssum = wave_sum(sv[0] + sv[1]);
        inv = 1.0f / ssum;
    }

    // ---- Phase C: P bf16 -> LDS (ping-pong halves), P.V MFMA; 1 barrier/segment ----
    int jt_o = (w & 7) * 16;
    int kh = (w >> 3) * 256;
    f32x4 acc_o = {0.f, 0.f, 0.f, 0.f};
    f32x2 inv2 = {inv, inv};

#pragma unroll
    for (int sgi = 0; sgi < SEGS; sgi++) {
        int j0 = sgi * 512;
        bf16 (*pb)[BROW] = (bf16(*)[BROW])(&buf[0][0]) + (sgi & 1) * 16;
#pragma unroll
        for (int part = 0; part < 2; part++) {
            f32x2 xa = __builtin_convertvector(xr[sgi * 4 + part * 2 + 0], f32x2);
            f32x2 xb = __builtin_convertvector(xr[sgi * 4 + part * 2 + 1], f32x2);
            f32x2 ta = __builtin_elementwise_max(xa - tv, z2);
            f32x2 tb = __builtin_elementwise_max(xb - tv, z2);
            f32x2 pa = (ta * ta) * inv2;
            f32x2 pb2 = (tb * tb) * inv2;
            bf16x4 pbv;
            pbv[0] = (bf16)pa[0]; pbv[1] = (bf16)pa[1];
            pbv[2] = (bf16)pb2[0]; pbv[3] = (bf16)pb2[1];
            *(bf16x4*)&pb[w][part * 256 + l * 4] = pbv;
        }
        __syncthreads();
#pragma unroll
        for (int ks = 0; ks < 8; ks++) {
            int kk = kh + ks * 32;
            bf16x8 a = *(const bf16x8*)&pb[lane16][kk + quad * 8];
            bf16x8 b = *(const bf16x8*)(vbase + (size_t)(jt_o + lane16) * S + j0 + kk + quad * 8);
            acc_o = __builtin_amdgcn_mfma_f32_16x16x32_bf16(a, b, acc_o, 0, 0, 0);
        }
        // no trailing barrier: next segment writes the other half; its barrier orders reuse
    }

    // ---- Phase D: combine K-halves, write O ----
    __syncthreads();  // all P.V MFMA reads done before buf reuse as f32
    if (w >= 8) {
#pragma unroll
        for (int r = 0; r < 4; r++) buf[w - 8][l * 4 + r] = acc_o[r];
    }
    __syncthreads();
    if (w < 8) {
        bf16* op = o + (size_t)(r0 + quad * 4) * DM + h * HD + jt_o + lane16;
#pragma unroll
        for (int r = 0; r < 4; r++) {
            float v = acc_o[r] + buf[w][l * 4 + r];
            op[(size_t)r * DM] = (bf16)v;
        }
    }

    // ---- Phase E: full attn row streaming write (P + zeros); no barrier after -> drains lazily ----
    float* arow = attn + ((size_t)h * S + (r0 + w)) * S;
#pragma unroll
    for (int sgi = 0; sgi < SEGS; sgi++) {
        int j0 = sgi * 512;
#pragma unroll
        for (int part = 0; part < 2; part++) {
            f32x2 xa = __builtin_convertvector(xr[sgi * 4 + part * 2 + 0], f32x2);
            f32x2 xb = __builtin_convertvector(xr[sgi * 4 + part * 2 + 1], f32x2);
            f32x2 ta = __builtin_elementwise_max(xa - tv, z2);
            f32x2 tb = __builtin_elementwise_max(xb - tv, z2);
            f32x2 pa = (ta * ta) * inv2;
            f32x2 pb2 = (tb * tb) * inv2;
            f32x4 pv = {pa[0], pa[1], pb2[0], pb2[1]};
            nt_store4(pv, &arow[j0 + part * 256 + l * 4]);
        }
    }
    f32x4 z4 = {0.f, 0.f, 0.f, 0.f};
    for (int j = SEGS * 512 + l * 4; j < S; j += 256) nt_store4(z4, &arow[j]);
}

// Persistent workgroups: 512 blocks (2/CU), each runs one item of every causal class
// {1,2,3,4} segments -> exactly 10 segments per block, perfectly uniform load.
// waves_per_eu(8) => 64 regs/lane total; body now fits (xr packed f16) -> no spill.
__global__ __attribute__((amdgpu_flat_work_group_size(1024, 1024), amdgpu_waves_per_eu(8)))
void attn_av_all(const bf16* __restrict__ qs,
                 const bf16* __restrict__ kb,
                 const bf16* __restrict__ vT,
                 float* __restrict__ attn,
                 bf16* __restrict__ o) {
    __shared__ float buf[16][BROW];  // ~35 KB -> 2 blocks/CU fit LDS
    int b = blockIdx.x;      // 0..511
    int h = b & 15;
    int qh = b >> 4;         // 0..31
    attn_body<4>(qs, kb, vT, attn, o, (96 + qh) * 16, h, buf);
    __syncthreads();
    attn_body<3>(qs, kb, vT, attn, o, (64 + qh) * 16, h, buf);
    __syncthreads();
    attn_body<2>(qs, kb, vT, attn, o, (32 + qh) * 16, h, buf);
    __syncthreads();
    attn_body<1>(qs, kb, vT, attn, o, qh * 16, h, buf);
}

extern "C" void kernel_launch(void* const* d_in, const int* in_sizes, int n_in,
                              void* d_out, int out_size, void* d_ws, size_t ws_size,
                              hipStream_t stream) {
    const float* hidden = (const float*)d_in[0];
    const float* cosb   = (const float*)d_in[1];
    const float* sinb   = (const float*)d_in[2];
    const float* wq     = (const float*)d_in[3];
    const float* wk     = (const float*)d_in[4];
    const float* wv     = (const float*)d_in[5];
    const float* wo     = (const float*)d_in[6];
    char* ws = (char*)d_ws;
    bf16*  bf_hidden = (bf16*)(ws);                    // 8 MB; reused as O bf16 later
    bf16*  bf_wqkv   = (bf16*)(ws + 8388608);          // 12 MB
    bf16*  bf_wo     = (bf16*)(ws + 20971520);         // 8 MB
    float* qkv_raw   = (float*)(ws + 29360128);        // 24 MB
    bf16*  qsb       = (bf16*)(ws + 54525952);         // 8 MB  [H][S][HD]
    bf16*  kbb       = (bf16*)(ws + 62914560);         // 2 MB  [4][S][HD]
    bf16*  vTb       = (bf16*)(ws + 65011712);         // 2 MB  [4][HD][S]
    float* out  = (float*)d_out;
    float* attn = out + 4194304;

    cvt_all<<<dim3(14336), 256, 0, stream>>>(hidden, wq, wk, wv, wo, bf_hidden, bf_wqkv, bf_wo);

    // QKV projection: [2048 x 2048] @ [3072 x 2048]^T
    gemm_bt<64, 128><<<dim3(32, 24), 256, 0, stream>>>(bf_hidden, bf_wqkv, qkv_raw, NQKV, DM);

    rope_qk<<<dim3(10, S), 256, 0, stream>>>(qkv_raw, cosb, sinb, qsb, kbb);
    vtrans<<<dim3(32, 8), 256, 0, stream>>>(qkv_raw, vTb);

    // fused scores + entmax + P.V + attn write  (512 persistent blocks, 2/CU)
    attn_av_all<<<dim3(512), 1024, 0, stream>>>(qsb, kbb, vTb, attn, bf_hidden);

    // out = O @ wo^T
    gemm_bt<64, 128><<<dim3(32, 16), 256, 0, stream>>>(bf_hidden, bf_wo, out, DM, DM);
}

// Round 5
// 585.491 us; speedup vs baseline: 1.0359x; 1.0359x over previous
//
#include <hip/hip_runtime.h>

typedef __bf16 bf16;
typedef __bf16 bf16x4 __attribute__((ext_vector_type(4)));
typedef __bf16 bf16x8 __attribute__((ext_vector_type(8)));
typedef float f32x4 __attribute__((ext_vector_type(4)));
typedef float f32x2 __attribute__((ext_vector_type(2)));
typedef _Float16 f16x2 __attribute__((ext_vector_type(2)));

#define S 2048
#define DM 2048
#define HD 128
#define H 16
#define NQKV 3072
#define NEWTON_ITERS 12
#define BROW 556         // f32 row stride of LDS buf; padding kept bank conflicts at 0 (R3/R4)
#define MASKV -30000.0f  // causal-mask value; f16-representable, dominates all real scores

__device__ __forceinline__ void gl2lds16(const void* g, void* l) {
    __builtin_amdgcn_global_load_lds(
        (const __attribute__((address_space(1))) void*)g,
        (__attribute__((address_space(3))) void*)l, 16, 0, 0);
}

__device__ __forceinline__ void nt_store4(f32x4 v, float* p) {
    __builtin_nontemporal_store(v, (f32x4*)p);
}

// ---------------- DPP-based wave(64) reductions: VALU-latency chains, no LDS pipe ----------------
template <int CTRL, int RM>
__device__ __forceinline__ float dpp_zero(float x) {  // invalid/disabled lanes contribute 0
    return __builtin_bit_cast(float, __builtin_amdgcn_update_dpp(
        0, __builtin_bit_cast(int, x), CTRL, RM, 0xf, false));
}
template <int CTRL, int RM>
__device__ __forceinline__ float dpp_self(float x) {  // invalid/disabled lanes contribute x (no-op for max)
    int xi = __builtin_bit_cast(int, x);
    return __builtin_bit_cast(float, __builtin_amdgcn_update_dpp(xi, xi, CTRL, RM, 0xf, false));
}
__device__ __forceinline__ float wave_bcast63(float x) {
    return __builtin_bit_cast(float, __builtin_amdgcn_readlane(__builtin_bit_cast(int, x), 63));
}
__device__ __forceinline__ float wave_sum(float x) {
    x += dpp_zero<0x111, 0xf>(x);  // row_shr:1
    x += dpp_zero<0x112, 0xf>(x);  // row_shr:2
    x += dpp_zero<0x114, 0xf>(x);  // row_shr:4
    x += dpp_zero<0x118, 0xf>(x);  // row_shr:8  -> lane15 of each row-of-16 = row sum
    x += dpp_zero<0x142, 0xa>(x);  // row_bcast:15 -> rows 1,3
    x += dpp_zero<0x143, 0xc>(x);  // row_bcast:31 -> rows 2,3; lane63 = total
    return wave_bcast63(x);
}
__device__ __forceinline__ float wave_fmax(float x) {
    x = fmaxf(x, dpp_self<0x111, 0xf>(x));
    x = fmaxf(x, dpp_self<0x112, 0xf>(x));
    x = fmaxf(x, dpp_self<0x114, 0xf>(x));
    x = fmaxf(x, dpp_self<0x118, 0xf>(x));
    x = fmaxf(x, dpp_self<0x142, 0xa>(x));
    x = fmaxf(x, dpp_self<0x143, 0xc>(x));
    return wave_bcast63(x);
}

// ---------------- fused fp32 -> bf16 convert for all 5 inputs (float4 granules) ----------------
__global__ void cvt_all(const float* __restrict__ hid, const float* __restrict__ wq,
                        const float* __restrict__ wk, const float* __restrict__ wv,
                        const float* __restrict__ wo, bf16* __restrict__ bh,
                        bf16* __restrict__ bqkv, bf16* __restrict__ bwo) {
    int i = blockIdx.x * blockDim.x + threadIdx.x;
    const float* src;
    bf16* dst;
    int off;
    if (i < 1048576) { src = hid; dst = bh; off = i; }
    else if (i < 2097152) { src = wq; dst = bqkv; off = i - 1048576; }
    else if (i < 2359296) { src = wk; dst = bqkv + 2048 * 2048; off = i - 2097152; }
    else if (i < 2621440) { src = wv; dst = bqkv + 2048 * 2048 + 512 * 2048; off = i - 2359296; }
    else { src = wo; dst = bwo; off = i - 2621440; }
    float4 f = ((const float4*)src)[off];
    bf16x4 o;
    o[0] = (bf16)f.x; o[1] = (bf16)f.y; o[2] = (bf16)f.z; o[3] = (bf16)f.w;
    ((bf16x4*)dst)[off] = o;
}

// ---------------- BMxBN-tile GEMM: C[m][n] = sum_k A[m][k]*B[n][k] ----------------
template <int BM, int BN>
__global__ __launch_bounds__(256) void gemm_bt(const bf16* __restrict__ A,
                                               const bf16* __restrict__ B,
                                               float* __restrict__ C, int Ndim, int K) {
    __shared__ bf16 As[BM * 32];
    __shared__ bf16 Bs[BN * 32];
    int m0 = blockIdx.x * BM, n0 = blockIdx.y * BN;
    int t = threadIdx.x;
    int l = t & 63, w = t >> 6;
    int lane16 = l & 15, quad = l >> 4;

    const bf16* Abase = A + (size_t)m0 * K;
    const bf16* Bbase = B + (size_t)n0 * K;

    constexpr int MI = BM / 32, NI = BN / 32;
    int wm = (w & 1) * (BM / 2), wn = (w >> 1) * (BN / 2);
    f32x4 acc[MI][NI];
#pragma unroll
    for (int i = 0; i < MI; i++)
#pragma unroll
        for (int j = 0; j < NI; j++) acc[i][j] = (f32x4){0.f, 0.f, 0.f, 0.f};

    constexpr int AG = BM * 4;  // 16B granules in A tile
    constexpr int BG = BN * 4;

    for (int k0 = 0; k0 < K; k0 += 32) {
#pragma unroll
        for (int it = 0; it < AG / 256; it++) {
            int c = it * 256 + t;  // granule index; c - l is wave-uniform
            gl2lds16(Abase + (size_t)(c >> 2) * K + k0 + (c & 3) * 8, &As[(c - l) * 8]);
        }
#pragma unroll
        for (int it = 0; it < BG / 256; it++) {
            int c = it * 256 + t;
            gl2lds16(Bbase + (size_t)(c >> 2) * K + k0 + (c & 3) * 8, &Bs[(c - l) * 8]);
        }
        __syncthreads();
        bf16x8 af[MI], bfr[NI];
#pragma unroll
        for (int i = 0; i < MI; i++)
            af[i] = *(const bf16x8*)&As[(wm + i * 16 + lane16) * 32 + quad * 8];
#pragma unroll
        for (int j = 0; j < NI; j++)
            bfr[j] = *(const bf16x8*)&Bs[(wn + j * 16 + lane16) * 32 + quad * 8];
#pragma unroll
        for (int i = 0; i < MI; i++)
#pragma unroll
            for (int j = 0; j < NI; j++)
                acc[i][j] = __builtin_amdgcn_mfma_f32_16x16x32_bf16(af[i], bfr[j], acc[i][j], 0, 0, 0);
        __syncthreads();
    }
#pragma unroll
    for (int i = 0; i < MI; i++)
#pragma unroll
        for (int j = 0; j < NI; j++) {
            float* cp = C + (size_t)(m0 + wm + i * 16 + quad * 4) * Ndim + n0 + wn + j * 16 + lane16;
#pragma unroll
            for (int r = 0; r < 4; r++) cp[(size_t)r * Ndim] = acc[i][j][r];
        }
}

// ---------------- RoPE for q/k (cols 0..2559), coalesced in col ----------------
__global__ void rope_qk(const float* __restrict__ qkv, const float* __restrict__ cosb,
                        const float* __restrict__ sinb, bf16* __restrict__ qs,
                        bf16* __restrict__ kb) {
    int col = blockIdx.x * 256 + threadIdx.x;  // 0..2559
    int s = blockIdx.y;
    const float* row = qkv + (size_t)s * NQKV;
    float v = row[col];
    if (col < DM) {
        int h = col >> 7, d = col & 127;
        float c = cosb[s * HD + d], sn = sinb[s * HD + d];
        float other = row[(h << 7) + ((d < 64) ? (d + 64) : (d - 64))];
        float rot = (d < 64) ? -other : other;
        float o = v * c + rot * sn;
        qs[((size_t)h * S + s) * HD + d] = (bf16)(o * 0.04419417382415922f);  // HD^-0.5 * (alpha-1)
    } else {
        int c2 = col - DM;
        int kv = c2 >> 7, d = c2 & 127;
        float c = cosb[s * HD + d], sn = sinb[s * HD + d];
        float other = row[DM + (kv << 7) + ((d < 64) ? (d + 64) : (d - 64))];
        float rot = (d < 64) ? -other : other;
        float o = v * c + rot * sn;
        kb[((size_t)kv * S + s) * HD + d] = (bf16)o;
    }
}

// ---------------- V transpose via LDS tile: qkv[s][2560+y] -> vT[y][s] bf16 ----------------
__global__ __launch_bounds__(256) void vtrans(const float* __restrict__ qkv, bf16* __restrict__ vT) {
    __shared__ bf16 tile[64][66];
    int s0 = blockIdx.x * 64, y0 = blockIdx.y * 64;
    int t = threadIdx.x;
    int ty = t & 63, tr = t >> 6;
#pragma unroll
    for (int i = 0; i < 16; i++) {
        int s = tr + i * 4;
        float v = qkv[(size_t)(s0 + s) * NQKV + 2560 + y0 + ty];  // coalesced read
        tile[s][ty] = (bf16)v;
    }
    __syncthreads();
#pragma unroll
    for (int i = 0; i < 16; i++) {
        int y = tr + i * 4;
        vT[(size_t)(y0 + y) * S + s0 + ty] = tile[ty][y];  // coalesced write
    }
}

// ------- fused: scores (MFMA) + causal mask + entmax Newton + P.V (MFMA) + attn write -------
// 8-wave (512-thread) blocks; each wave owns TWO rows (w, w+8) of the 16-row tile.
// Per-lane score state: xr0+xr1 = 32 VGPR (f16-packed). waves_per_eu(6) -> ~85-reg budget,
// 3 blocks/CU co-resident (6 waves/SIMD = 75% occupancy) without scratch spill.
template <int SEGS>
__device__ __forceinline__ void attn_body(const bf16* __restrict__ qs, const bf16* __restrict__ kb,
                                          const bf16* __restrict__ vT, float* __restrict__ attn,
                                          bf16* __restrict__ o, int r0, int h,
                                          float (&buf)[16][BROW]) {
    constexpr int NR = SEGS * 4;  // f16x2 regs per ROW per lane
    int jlen = r0 + 16;
    int l = threadIdx.x & 63;
    int w = threadIdx.x >> 6;  // 0..7
    int lane16 = l & 15, quad = l >> 4;

    const bf16* qrow = qs + ((size_t)h * S + (r0 + lane16)) * HD + quad * 8;
    bf16x8 afrag[4];
#pragma unroll
    for (int kc = 0; kc < 4; kc++) afrag[kc] = *(const bf16x8*)(qrow + kc * 32);

    const bf16* kbase = kb + (size_t)(h >> 2) * S * HD;
    const bf16* vbase = vT + (size_t)(h >> 2) * HD * S;
    f16x2 xr0[NR], xr1[NR];

    // ---- Phase A: scores; each wave computes 4 j-subtiles, reads back rows w and w+8 ----
#pragma unroll
    for (int sgi = 0; sgi < SEGS; sgi++) {
        int j0 = sgi * 512;
#pragma unroll
        for (int tt = 0; tt < 4; tt++) {
            int jt = j0 + (w + tt * 8) * 16;
            if (jt < jlen) {
                f32x4 acc = {0.f, 0.f, 0.f, 0.f};
                const bf16* kp = kbase + (size_t)(jt + lane16) * HD + quad * 8;
#pragma unroll
                for (int kc = 0; kc < 4; kc++) {
                    bf16x8 bfr = *(const bf16x8*)(kp + kc * 32);
                    acc = __builtin_amdgcn_mfma_f32_16x16x32_bf16(afrag[kc], bfr, acc, 0, 0, 0);
                }
                int tcol = (w + tt * 8) * 16 + lane16;
                if (jt + 15 > r0) {  // diagonal tile: apply causal mask
                    int jj = jt + lane16;
#pragma unroll
                    for (int r = 0; r < 4; r++) {
                        int rowi = quad * 4 + r;
                        float v = acc[r];
                        if (jj > r0 + rowi) v = MASKV;
                        buf[rowi][tcol] = v;
                    }
                } else {
#pragma unroll
                    for (int r = 0; r < 4; r++) buf[quad * 4 + r][tcol] = acc[r];
                }
            }
        }
        __syncthreads();
#pragma unroll
        for (int part = 0; part < 2; part++) {
            float4 fq0 = *(const float4*)&buf[w][part * 256 + l * 4];
            float4 fq1 = *(const float4*)&buf[w + 8][part * 256 + l * 4];
            f32x2 a0, b0, a1, b1;
            if (sgi == SEGS - 1) {
                int jb = j0 + part * 256 + l * 4;
                bool c0 = jb + 0 < jlen, c1 = jb + 1 < jlen, c2 = jb + 2 < jlen, c3 = jb + 3 < jlen;
                a0 = (f32x2){c0 ? fq0.x : MASKV, c1 ? fq0.y : MASKV};
                b0 = (f32x2){c2 ? fq0.z : MASKV, c3 ? fq0.w : MASKV};
                a1 = (f32x2){c0 ? fq1.x : MASKV, c1 ? fq1.y : MASKV};
                b1 = (f32x2){c2 ? fq1.z : MASKV, c3 ? fq1.w : MASKV};
            } else {
                a0 = (f32x2){fq0.x, fq0.y}; b0 = (f32x2){fq0.z, fq0.w};
                a1 = (f32x2){fq1.x, fq1.y}; b1 = (f32x2){fq1.z, fq1.w};
            }
            xr0[sgi * 4 + part * 2 + 0] = __builtin_convertvector(a0, f16x2);
            xr0[sgi * 4 + part * 2 + 1] = __builtin_convertvector(b0, f16x2);
            xr1[sgi * 4 + part * 2 + 0] = __builtin_convertvector(a1, f16x2);
            xr1[sgi * 4 + part * 2 + 1] = __builtin_convertvector(b1, f16x2);
        }
        __syncthreads();  // all reads done before next segment's writes
    }

    // ---- Phase B: Newton for BOTH rows; 4 independent DPP reduce chains per iter ----
    const f32x2 z2 = {0.f, 0.f};
    float mx0 = MASKV, mx1 = MASKV;
#pragma unroll
    for (int c = 0; c < NR; c++) {
        f32x2 x0 = __builtin_convertvector(xr0[c], f32x2);
        f32x2 x1 = __builtin_convertvector(xr1[c], f32x2);
        mx0 = fmaxf(mx0, fmaxf(x0[0], x0[1]));
        mx1 = fmaxf(mx1, fmaxf(x1[0], x1[1]));
    }
    float tau0 = wave_fmax(mx0) - 1.0f;
    float tau1 = wave_fmax(mx1) - 1.0f;
#pragma unroll 1
    for (int it = 0; it < NEWTON_ITERS; it++) {
        f32x2 tv0i = {tau0, tau0}, tv1i = {tau1, tau1};
        f32x2 fa0 = z2, ga0 = z2, fa1 = z2, ga1 = z2;
#pragma unroll
        for (int c = 0; c < NR; c++) {
            f32x2 x0 = __builtin_convertvector(xr0[c], f32x2);
            f32x2 d0 = __builtin_elementwise_max(x0 - tv0i, z2);
            fa0 += d0 * d0; ga0 += d0;
            f32x2 x1 = __builtin_convertvector(xr1[c], f32x2);
            f32x2 d1 = __builtin_elementwise_max(x1 - tv1i, z2);
            fa1 += d1 * d1; ga1 += d1;
        }
        float f0 = wave_sum(fa0[0] + fa0[1]);
        float g0 = wave_sum(ga0[0] + ga0[1]);
        float f1 = wave_sum(fa1[0] + fa1[1]);
        float g1 = wave_sum(ga1[0] + ga1[1]);
        tau0 += (f0 - 1.0f) / (2.0f * g0 + 1e-20f);
        tau1 += (f1 - 1.0f) / (2.0f * g1 + 1e-20f);
    }

    f32x2 tv0 = {tau0, tau0}, tv1 = {tau1, tau1};
    float inv0, inv1;
    {
        f32x2 sa0 = z2, sa1 = z2;
#pragma unroll
        for (int c = 0; c < NR; c++) {
            f32x2 x0 = __builtin_convertvector(xr0[c], f32x2);
            f32x2 d0 = __builtin_elementwise_max(x0 - tv0, z2);
            sa0 += d0 * d0;
            f32x2 x1 = __builtin_convertvector(xr1[c], f32x2);
            f32x2 d1 = __builtin_elementwise_max(x1 - tv1, z2);
            sa1 += d1 * d1;
        }
        inv0 = 1.0f / wave_sum(sa0[0] + sa0[1]);
        inv1 = 1.0f / wave_sum(sa1[0] + sa1[1]);
    }

    // ---- Phase C: P bf16 -> LDS (ping-pong halves), P.V MFMA (full K per wave) ----
    int jt_o = w * 16;
    f32x4 acc_o = {0.f, 0.f, 0.f, 0.f};
    f32x2 i0 = {inv0, inv0}, i1 = {inv1, inv1};

#pragma unroll
    for (int sgi = 0; sgi < SEGS; sgi++) {
        int j0 = sgi * 512;
        bf16 (*pb)[BROW] = (bf16(*)[BROW])(&buf[0][0]) + (sgi & 1) * 16;
#pragma unroll
        for (int part = 0; part < 2; part++) {
            f32x2 xa = __builtin_convertvector(xr0[sgi * 4 + part * 2 + 0], f32x2);
            f32x2 xb = __builtin_convertvector(xr0[sgi * 4 + part * 2 + 1], f32x2);
            f32x2 da = __builtin_elementwise_max(xa - tv0, z2);
            f32x2 db = __builtin_elementwise_max(xb - tv0, z2);
            f32x2 pa = (da * da) * i0;
            f32x2 pc = (db * db) * i0;
            bf16x4 pv;
            pv[0] = (bf16)pa[0]; pv[1] = (bf16)pa[1]; pv[2] = (bf16)pc[0]; pv[3] = (bf16)pc[1];
            *(bf16x4*)&pb[w][part * 256 + l * 4] = pv;
            xa = __builtin_convertvector(xr1[sgi * 4 + part * 2 + 0], f32x2);
            xb = __builtin_convertvector(xr1[sgi * 4 + part * 2 + 1], f32x2);
            da = __builtin_elementwise_max(xa - tv1, z2);
            db = __builtin_elementwise_max(xb - tv1, z2);
            pa = (da * da) * i1;
            pc = (db * db) * i1;
            pv[0] = (bf16)pa[0]; pv[1] = (bf16)pa[1]; pv[2] = (bf16)pc[0]; pv[3] = (bf16)pc[1];
            *(bf16x4*)&pb[w + 8][part * 256 + l * 4] = pv;
        }
        __syncthreads();
#pragma unroll
        for (int ks = 0; ks < 16; ks++) {
            int kk = ks * 32;
            bf16x8 a = *(const bf16x8*)&pb[lane16][kk + quad * 8];
            bf16x8 bv = *(const bf16x8*)(vbase + (size_t)(jt_o + lane16) * S + j0 + kk + quad * 8);
            acc_o = __builtin_amdgcn_mfma_f32_16x16x32_bf16(a, bv, acc_o, 0, 0, 0);
        }
        // no trailing barrier: next segment writes the other half; its barrier orders reuse
    }

    // ---- Phase D: direct O write (full K per wave -> no split-K combine) ----
    bf16* op = o + (size_t)(r0 + quad * 4) * DM + h * HD + jt_o + lane16;
#pragma unroll
    for (int r = 0; r < 4; r++) op[(size_t)r * DM] = (bf16)acc_o[r];

    // ---- Phase E: attn rows w and w+8 streaming write (P + zeros); drains lazily ----
    float* arow0 = attn + ((size_t)h * S + (r0 + w)) * S;
    float* arow1 = arow0 + (size_t)8 * S;
#pragma unroll
    for (int sgi = 0; sgi < SEGS; sgi++) {
        int j0 = sgi * 512;
#pragma unroll
        for (int part = 0; part < 2; part++) {
            f32x2 xa = __builtin_convertvector(xr0[sgi * 4 + part * 2 + 0], f32x2);
            f32x2 xb = __builtin_convertvector(xr0[sgi * 4 + part * 2 + 1], f32x2);
            f32x2 da = __builtin_elementwise_max(xa - tv0, z2);
            f32x2 db = __builtin_elementwise_max(xb - tv0, z2);
            f32x2 pa = (da * da) * i0;
            f32x2 pc = (db * db) * i0;
            f32x4 pv0 = {pa[0], pa[1], pc[0], pc[1]};
            nt_store4(pv0, &arow0[j0 + part * 256 + l * 4]);
            xa = __builtin_convertvector(xr1[sgi * 4 + part * 2 + 0], f32x2);
            xb = __builtin_convertvector(xr1[sgi * 4 + part * 2 + 1], f32x2);
            da = __builtin_elementwise_max(xa - tv1, z2);
            db = __builtin_elementwise_max(xb - tv1, z2);
            pa = (da * da) * i1;
            pc = (db * db) * i1;
            f32x4 pv1 = {pa[0], pa[1], pc[0], pc[1]};
            nt_store4(pv1, &arow1[j0 + part * 256 + l * 4]);
        }
    }
    f32x4 z4 = {0.f, 0.f, 0.f, 0.f};
    for (int j = SEGS * 512 + l * 4; j < S; j += 256) {
        nt_store4(z4, &arow0[j]);
        nt_store4(z4, &arow1[j]);
    }
}

// 768 blocks x 512 threads = 3 blocks/CU at 6 waves/SIMD (75% occupancy).
// Work split: blocks [0,512) run classes {4,2,1} = 7 segs; blocks [512,768) run
// two class-3 tiles = 6 segs. Heavy blocks dispatch first.
__global__ __attribute__((amdgpu_flat_work_group_size(512, 512), amdgpu_waves_per_eu(6)))
void attn_av_all(const bf16* __restrict__ qs,
                 const bf16* __restrict__ kb,
                 const bf16* __restrict__ vT,
                 float* __restrict__ attn,
                 bf16* __restrict__ o) {
    __shared__ float buf[16][BROW];  // ~35 KB -> 3 blocks/CU fit LDS (105 KB)
    int b = blockIdx.x;
    if (b < 512) {
        int h = b & 15;
        int qh = b >> 4;  // 0..31
        attn_body<4>(qs, kb, vT, attn, o, (96 + qh) * 16, h, buf);
        __syncthreads();
        attn_body<2>(qs, kb, vT, attn, o, (32 + qh) * 16, h, buf);
        __syncthreads();
        attn_body<1>(qs, kb, vT, attn, o, qh * 16, h, buf);
    } else {
        int b2 = b - 512;
        int h = b2 & 15;
        int q2 = b2 >> 4;  // 0..15
        attn_body<3>(qs, kb, vT, attn, o, (64 + 2 * q2) * 16, h, buf);
        __syncthreads();
        attn_body<3>(qs, kb, vT, attn, o, (64 + 2 * q2 + 1) * 16, h, buf);
    }
}

extern "C" void kernel_launch(void* const* d_in, const int* in_sizes, int n_in,
                              void* d_out, int out_size, void* d_ws, size_t ws_size,
                              hipStream_t stream) {
    const float* hidden = (const float*)d_in[0];
    const float* cosb   = (const float*)d_in[1];
    const float* sinb   = (const float*)d_in[2];
    const float* wq     = (const float*)d_in[3];
    const float* wk     = (const float*)d_in[4];
    const float* wv     = (const float*)d_in[5];
    const float* wo     = (const float*)d_in[6];
    char* ws = (char*)d_ws;
    bf16*  bf_hidden = (bf16*)(ws);                    // 8 MB; reused as O bf16 later
    bf16*  bf_wqkv   = (bf16*)(ws + 8388608);          // 12 MB
    bf16*  bf_wo     = (bf16*)(ws + 20971520);         // 8 MB
    float* qkv_raw   = (float*)(ws + 29360128);        // 24 MB
    bf16*  qsb       = (bf16*)(ws + 54525952);         // 8 MB  [H][S][HD]
    bf16*  kbb       = (bf16*)(ws + 62914560);         // 2 MB  [4][S][HD]
    bf16*  vTb       = (bf16*)(ws + 65011712);         // 2 MB  [4][HD][S]
    float* out  = (float*)d_out;
    float* attn = out + 4194304;

    cvt_all<<<dim3(14336), 256, 0, stream>>>(hidden, wq, wk, wv, wo, bf_hidden, bf_wqkv, bf_wo);

    // QKV projection: [2048 x 2048] @ [3072 x 2048]^T
    gemm_bt<64, 128><<<dim3(32, 24), 256, 0, stream>>>(bf_hidden, bf_wqkv, qkv_raw, NQKV, DM);

    rope_qk<<<dim3(10, S), 256, 0, stream>>>(qkv_raw, cosb, sinb, qsb, kbb);
    vtrans<<<dim3(32, 8), 256, 0, stream>>>(qkv_raw, vTb);

    // fused scores + entmax + P.V + attn write  (768 blocks x 512 threads, 3/CU)
    attn_av_all<<<dim3(768), 512, 0, stream>>>(qsb, kbb, vTb, attn, bf_hidden);

    // out = O @ wo^T
    gemm_bt<64, 128><<<dim3(32, 16), 256, 0, stream>>>(bf_hidden, bf_wo, out, DM, DM);
}